// Round 4
// baseline (565.466 us; speedup 1.0000x reference)
//
#include <hip/hip_runtime.h>

constexpr int N_NODES = 50000;
constexpr int N_EDGES = 800000;
constexpr int NBINS   = 782;     // ceil(50000/64), 64 nodes per bin
constexpr int BINCAP  = 1536;    // mean 1024, sd 32 -> +16 sigma, never overflows
constexpr int FILL_BLOCKS = 261; // 261*3072 >= 800000
constexpr int PLANE   = 600000;  // ushorts per column-plane (50000*12)

typedef __attribute__((ext_vector_type(8))) short short8;
typedef __attribute__((ext_vector_type(8))) unsigned short ushort8;
typedef __attribute__((ext_vector_type(4))) short short4v;
typedef __attribute__((ext_vector_type(4))) unsigned short ushort4v;
typedef __attribute__((ext_vector_type(4))) float floatx4;

static __device__ __forceinline__ unsigned short f2bf(float f) {
    unsigned u = __float_as_uint(f);
    u += 0x7FFF + ((u >> 16) & 1);
    return (unsigned short)(u >> 16);
}
static __device__ __forceinline__ float bf2f(unsigned short s) {
    return __uint_as_float(((unsigned)s) << 16);
}

// ---------------- K1: fused prep + edge binning.
// Blocks [0,261): edge binning (bin_cnt pre-zeroed by memset node).
// Blocks [261,2605): x -> xb (row-major bf16) AND xbp (8 column-planes of
//   12 cols, 1.2 MB each — sized to be L2-resident per XCD in k_agg);
//   W transpose->bf16; zero g; out = b2-init for split-K mlp2.
__global__ __launch_bounds__(256) void k_prep_fill(const float* __restrict__ x,
                                                   unsigned short* __restrict__ xb,
                                                   unsigned short* __restrict__ xbp,
                                                   const float* __restrict__ Wrel,
                                                   const float* __restrict__ Wroot,
                                                   unsigned short* __restrict__ wt,
                                                   float* __restrict__ g,
                                                   const float* __restrict__ b2,
                                                   float* __restrict__ out,
                                                   const int* __restrict__ ei,
                                                   int* __restrict__ bin_cnt,
                                                   int* __restrict__ eb) {
    __shared__ int h[NBINS];
    __shared__ int gbase[NBINS];
    int t = threadIdx.x;
    if (blockIdx.x < FILL_BLOCKS) {
        for (int b = t; b < NBINS; b += 256) h[b] = 0;
        __syncthreads();
        int e0 = blockIdx.x * 3072;
#pragma unroll
        for (int i = 0; i < 12; i++) {
            int e = e0 + i * 256 + t;
            if (e < N_EDGES) atomicAdd(&h[ei[N_EDGES + e] >> 6], 1);
        }
        __syncthreads();
        for (int b = t; b < NBINS; b += 256) {
            int c = h[b];
            gbase[b] = c ? atomicAdd(&bin_cnt[b], c) : 0;
            h[b] = 0;
        }
        __syncthreads();
#pragma unroll
        for (int i = 0; i < 12; i++) {
            int e = e0 + i * 256 + t;
            if (e < N_EDGES) {
                int s = ei[e];
                int d = ei[N_EDGES + e];
                int bin = d >> 6;
                int p = gbase[bin] + atomicAdd(&h[bin], 1);
                if (p < BINCAP)                   // hardening: never write OOB
                    eb[bin * BINCAP + p] = (s << 6) | (d & 63);
            }
        }
        return;
    }
    // ---- prep part
    int idx = (blockIdx.x - FILL_BLOCKS) * 256 + t;
    if (idx < 49152) {                                  // Wt[n][k] = bf16(Wcat[k][n])
        int k = idx % 192;
        int n = idx / 192;
        float v = (k < 96) ? Wrel[k * 256 + n] : Wroot[(k - 96) * 256 + n];
        wt[idx] = f2bf(v);
    }
    if (idx < 16384) {
        reinterpret_cast<float4*>(g)[idx] = make_float4(0.f, 0.f, 0.f, 0.f);
    }
    if (idx < 256 * 768) out[idx] = b2[idx % 768];      // bias-init for split-K mlp2
    if (idx < 400000) {                                 // column planes for k_agg
        int p    = idx / 50000;
        int node = idx - p * 50000;
        const float4* q = reinterpret_cast<const float4*>(x + node * 96 + p * 12);
        float4 f0 = q[0], f1 = q[1], f2 = q[2];
        ushort4v r0, r1, r2;
        r0[0] = f2bf(f0.x); r0[1] = f2bf(f0.y); r0[2] = f2bf(f0.z); r0[3] = f2bf(f0.w);
        r1[0] = f2bf(f1.x); r1[1] = f2bf(f1.y); r1[2] = f2bf(f1.z); r1[3] = f2bf(f1.w);
        r2[0] = f2bf(f2.x); r2[1] = f2bf(f2.y); r2[2] = f2bf(f2.z); r2[3] = f2bf(f2.w);
        unsigned short* dp = xbp + p * PLANE + node * 12;
        *reinterpret_cast<ushort4v*>(dp)     = r0;
        *reinterpret_cast<ushort4v*>(dp + 4) = r1;
        *reinterpret_cast<ushort4v*>(dp + 8) = r2;
    }
    if (idx >= N_NODES * 96 / 8) return;
    const float4* p = reinterpret_cast<const float4*>(x) + idx * 2;
    float4 u = p[0], v = p[1];
    short8 a;
    a[0] = (short)f2bf(u.x); a[1] = (short)f2bf(u.y);
    a[2] = (short)f2bf(u.z); a[3] = (short)f2bf(u.w);
    a[4] = (short)f2bf(v.x); a[5] = (short)f2bf(v.y);
    a[6] = (short)f2bf(v.z); a[7] = (short)f2bf(v.w);
    reinterpret_cast<short8*>(xb)[idx] = a;
}

// ---------------- K2: XCD-local gather. Block (bin, cg) with cg = bid&7.
// blockIdx%8 -> XCD is the measured round-robin dispatch mapping, so every
// block on XCD p gathers ONLY from plane p (1.2 MB, L2-resident). Fetch
// drops 63 MB (replicated random rows) -> ~10 MB compulsory + coalesced eb.
// Edge-parallel with LDS float atomics: no per-cg sort needed.
__global__ __launch_bounds__(256) void k_agg(const int* __restrict__ bin_cnt,
                                             const int* __restrict__ eb,
                                             const unsigned short* __restrict__ xbp,
                                             unsigned short* __restrict__ agg) {
    __shared__ float at[64 * 12];
    const int bid = blockIdx.x;
    const int bin = bid >> 3, cg = bid & 7;
    const int t = threadIdx.x;
    const int total = min(bin_cnt[bin], BINCAP);
    const int* ebb = eb + bin * BINCAP;
    const unsigned short* xp = xbp + cg * PLANE;
    for (int j = t; j < 768; j += 256) at[j] = 0.f;
    __syncthreads();
    for (int i = t; i < total; i += 256) {
        int m = ebb[i];
        int s = m >> 6, d = (m & 63) * 12;
        ushort4v v0 = *reinterpret_cast<const ushort4v*>(xp + s * 12);
        ushort4v v1 = *reinterpret_cast<const ushort4v*>(xp + s * 12 + 4);
        ushort4v v2 = *reinterpret_cast<const ushort4v*>(xp + s * 12 + 8);
#pragma unroll
        for (int j = 0; j < 4; j++) {
            atomicAdd(&at[d + j],     bf2f(v0[j]));
            atomicAdd(&at[d + 4 + j], bf2f(v1[j]));
            atomicAdd(&at[d + 8 + j], bf2f(v2[j]));
        }
    }
    __syncthreads();
    if (t < 64) {
        ushort4v r0, r1, r2;
#pragma unroll
        for (int j = 0; j < 4; j++) {
            r0[j] = f2bf(at[t * 12 + j]);
            r1[j] = f2bf(at[t * 12 + 4 + j]);
            r2[j] = f2bf(at[t * 12 + 8 + j]);
        }
        unsigned short* dst = agg + (bin * 64 + t) * 96 + cg * 12;
        *reinterpret_cast<ushort4v*>(dst)     = r0;
        *reinterpret_cast<ushort4v*>(dst + 4) = r1;
        *reinterpret_cast<ushort4v*>(dst + 8) = r2;
    }
}

// ---------------- K3: GEMM 64x256x192 + bias/relu/segment-max pool.
// One 256-thr block per bin (4 waves x 64-col slice, round-0 structure);
// A-operand rows stream from agg (cols 0..95) and xb (cols 96..191).
__global__ __launch_bounds__(256, 4) void k_gemm(const unsigned short* __restrict__ agg,
                                                 const unsigned short* __restrict__ xb,
                                                 const unsigned short* __restrict__ wt,
                                                 const float* __restrict__ b_rel,
                                                 const int* __restrict__ batch,
                                                 int* __restrict__ g_i) {
    const int b = blockIdx.x, t = threadIdx.x;
    const int lane = t & 63;
    const int wave = t >> 6;
    const int quad = lane >> 4;
    const int l15  = lane & 15;
    const int row_base = b * 64;
    const int n0 = wave * 64;

    floatx4 C[4][4];
#pragma unroll
    for (int i = 0; i < 4; i++)
#pragma unroll
        for (int j = 0; j < 4; j++) C[i][j] = (floatx4)0.0f;

#pragma unroll
    for (int kc = 0; kc < 6; kc++) {
        short8 a4[4];
#pragma unroll
        for (int mf = 0; mf < 4; mf++) {
            if (kc < 3) {
                a4[mf] = *reinterpret_cast<const short8*>(
                    agg + (row_base + mf * 16 + l15) * 96 + kc * 32 + quad * 8);
            } else {
                int r = row_base + mf * 16 + l15;
                a4[mf] = (r < N_NODES)
                    ? *reinterpret_cast<const short8*>(xb + r * 96 + (kc - 3) * 32 + quad * 8)
                    : (short8)0;
            }
        }
        short8 b4[4];
#pragma unroll
        for (int nf = 0; nf < 4; nf++)
            b4[nf] = *reinterpret_cast<const short8*>(
                wt + (n0 + nf * 16 + l15) * 192 + kc * 32 + quad * 8);
#pragma unroll
        for (int mf = 0; mf < 4; mf++)
#pragma unroll
            for (int nf = 0; nf < 4; nf++)
                C[mf][nf] = __builtin_amdgcn_mfma_f32_16x16x32_bf16(
                    a4[mf], b4[nf], C[mf][nf], 0, 0, 0);
    }

    // ---- bias + relu + segment-max pool
    bool fast = (row_base + 63 < N_NODES) && (batch[row_base] == batch[row_base + 63]);
    if (fast) {
        int gid = batch[row_base];
#pragma unroll
        for (int nf = 0; nf < 4; nf++) {
            float m = C[0][nf][0];
#pragma unroll
            for (int mf = 0; mf < 4; mf++)
#pragma unroll
                for (int r = 0; r < 4; r++) m = fmaxf(m, C[mf][nf][r]);
            m = fmaxf(m, __shfl_xor(m, 16));
            m = fmaxf(m, __shfl_xor(m, 32));
            if (quad == 0) {
                int n = n0 + nf * 16 + l15;
                float v = fmaxf(m + b_rel[n], 0.0f);
                atomicMax(&g_i[gid * 256 + n], __float_as_int(v));
            }
        }
    } else {
#pragma unroll
        for (int mf = 0; mf < 4; mf++) {
            int rb = row_base + mf * 16 + quad * 4;
            if (rb >= N_NODES) continue;
            bool merged = (rb + 3 < N_NODES) && (batch[rb] == batch[rb + 3]);
            if (merged) {
                int gid = batch[rb];
#pragma unroll
                for (int nf = 0; nf < 4; nf++) {
                    float m = fmaxf(fmaxf(C[mf][nf][0], C[mf][nf][1]),
                                    fmaxf(C[mf][nf][2], C[mf][nf][3]));
                    int n = n0 + nf * 16 + l15;
                    float v = fmaxf(m + b_rel[n], 0.0f);
                    atomicMax(&g_i[gid * 256 + n], __float_as_int(v));
                }
            } else {
                for (int r = 0; r < 4; r++) {
                    int rg = rb + r;
                    if (rg >= N_NODES) break;
                    int gid = batch[rg];
#pragma unroll
                    for (int nf = 0; nf < 4; nf++) {
                        int n = n0 + nf * 16 + l15;
                        float v = fmaxf(C[mf][nf][r] + b_rel[n], 0.0f);
                        atomicMax(&g_i[gid * 256 + n], __float_as_int(v));
                    }
                }
            }
        }
    }
}

// ---------------- K4: g2 = relu(g @ W1 + b1). Round-2 version (proven):
// 512 blocks = 2048 waves; parallelism is the lever, not reuse.
__global__ __launch_bounds__(256) void k_mlp1(const float* __restrict__ g,
                                              const float* __restrict__ W1,
                                              const float* __restrict__ b1,
                                              float* __restrict__ g2) {
    __shared__ float sg[256];
    int m = blockIdx.x;
    int n = blockIdx.y * 256 + threadIdx.x;
    int t = threadIdx.x;
    sg[t] = g[m * 256 + t];
    __syncthreads();
    float a0 = 0.f, a1 = 0.f;
#pragma unroll 4
    for (int k = 0; k < 128; k++) {
        a0 += sg[k]       * W1[k * 512 + n];
        a1 += sg[k + 128] * W1[(k + 128) * 512 + n];
    }
    g2[m * 512 + n] = fmaxf(a0 + a1 + b1[n], 0.f);
}

// ---------------- K5: out += g2 @ W2 (split-K x4, out pre-init'd with b2).
// Round-2 version (proven). NO grid.sync — cooperative sync cost ~100us (R3).
__global__ __launch_bounds__(256) void k_mlp2(const float* __restrict__ g2,
                                              const float* __restrict__ W2,
                                              float* __restrict__ out) {
    __shared__ float sg[4 * 128];
    int m0 = blockIdx.x * 4;
    int n  = blockIdx.y * 256 + threadIdx.x;
    int k0 = blockIdx.z * 128;
    int t  = threadIdx.x;
#pragma unroll
    for (int j = t; j < 512; j += 256)
        sg[j] = g2[(m0 + (j >> 7)) * 512 + k0 + (j & 127)];
    __syncthreads();
    float a[4];
#pragma unroll
    for (int i = 0; i < 4; i++) a[i] = 0.f;
#pragma unroll 4
    for (int k = 0; k < 128; k++) {
        float w = W2[(k0 + k) * 768 + n];
#pragma unroll
        for (int i = 0; i < 4; i++) a[i] += sg[i * 128 + k] * w;
    }
#pragma unroll
    for (int i = 0; i < 4; i++)
        atomicAdd(&out[(m0 + i) * 768 + n], a[i]);
}

extern "C" void kernel_launch(void* const* d_in, const int* in_sizes, int n_in,
                              void* d_out, int out_size, void* d_ws, size_t ws_size,
                              hipStream_t stream) {
    const float* x      = (const float*)d_in[0];
    const int*   ei     = (const int*)d_in[1];
    const int*   batch  = (const int*)d_in[2];
    const float* W_rel  = (const float*)d_in[3];
    const float* b_rel  = (const float*)d_in[4];
    const float* W_root = (const float*)d_in[5];
    const float* W1     = (const float*)d_in[6];
    const float* b1     = (const float*)d_in[7];
    const float* W2     = (const float*)d_in[8];
    const float* b2     = (const float*)d_in[9];
    float* out = (float*)d_out;

    char* ws = (char*)d_ws;
    unsigned short* xb  = (unsigned short*)(ws);             //  9,600,000
    unsigned short* xbp = (unsigned short*)(ws + 9600000);   //  9,600,000 (8 planes)
    float* g       = (float*)(ws + 19200000);                //    262,144
    int* bin_cnt   = (int*)  (ws + 19462144);                //      3,136 (784 ints)
    int* eb        = (int*)  (ws + 19465280);                //  4,804,608 (782*1536*4)
    unsigned short* agg = (unsigned short*)(ws + 24269888);  //  9,609,216 (782*64*96*2)
    float* g2      = (float*)(ws + 33879104);                //    524,288
    unsigned short* wt = (unsigned short*)(ws + 34403392);   //     98,304
    // total ~34.5 MB

    hipMemsetAsync(bin_cnt, 0, 784 * sizeof(int), stream);
    k_prep_fill<<<FILL_BLOCKS + 2344, 256, 0, stream>>>(x, xb, xbp, W_rel, W_root,
                                                        wt, g, b2, out, ei, bin_cnt, eb);
    k_agg<<<NBINS * 8, 256, 0, stream>>>(bin_cnt, eb, xbp, agg);
    k_gemm<<<NBINS, 256, 0, stream>>>(agg, xb, wt, b_rel, batch, (int*)g);
    k_mlp1<<<dim3(256, 2), 256, 0, stream>>>(g, W1, b1, g2);
    k_mlp2<<<dim3(64, 3, 4), 256, 0, stream>>>(g2, W2, out);
}

// Round 5
// 211.368 us; speedup vs baseline: 2.6753x; 2.6753x over previous
//
#include <hip/hip_runtime.h>

constexpr int N_NODES = 50000;
constexpr int N_EDGES = 800000;
constexpr int NBINS   = 782;     // ceil(50000/64), 64 nodes per bin
constexpr int BINCAP  = 1536;    // mean 1024, sd 32 -> +16 sigma, never overflows
constexpr int FILL_BLOCKS = 261; // 261*3072 >= 800000
constexpr int PLANE   = 800000;  // ushorts per column-plane (50000 * 16, 12 real + 4 pad)

typedef __attribute__((ext_vector_type(8))) short short8;
typedef __attribute__((ext_vector_type(8))) unsigned short ushort8;
typedef __attribute__((ext_vector_type(4))) short short4v;
typedef __attribute__((ext_vector_type(4))) unsigned short ushort4v;
typedef __attribute__((ext_vector_type(4))) float floatx4;

static __device__ __forceinline__ unsigned short f2bf(float f) {
    unsigned u = __float_as_uint(f);
    u += 0x7FFF + ((u >> 16) & 1);
    return (unsigned short)(u >> 16);
}
static __device__ __forceinline__ float bf2f(unsigned short s) {
    return __uint_as_float(((unsigned)s) << 16);
}

// ---------------- K1: fused prep + edge binning.
// Blocks [0,261): edge binning (bin_cnt pre-zeroed by memset node).
// Blocks [261,2605): x -> xb (row-major bf16) AND xbp (8 column-planes of
//   12 real + 4 pad cols, 1.6 MB each — L2-resident per XCD in k_agg);
//   W transpose->bf16; zero g; out = b2-init for split-K mlp2.
__global__ __launch_bounds__(256) void k_prep_fill(const float* __restrict__ x,
                                                   unsigned short* __restrict__ xb,
                                                   unsigned short* __restrict__ xbp,
                                                   const float* __restrict__ Wrel,
                                                   const float* __restrict__ Wroot,
                                                   unsigned short* __restrict__ wt,
                                                   float* __restrict__ g,
                                                   const float* __restrict__ b2,
                                                   float* __restrict__ out,
                                                   const int* __restrict__ ei,
                                                   int* __restrict__ bin_cnt,
                                                   int* __restrict__ eb) {
    __shared__ int h[NBINS];
    __shared__ int gbase[NBINS];
    int t = threadIdx.x;
    if (blockIdx.x < FILL_BLOCKS) {
        for (int b = t; b < NBINS; b += 256) h[b] = 0;
        __syncthreads();
        int e0 = blockIdx.x * 3072;
#pragma unroll
        for (int i = 0; i < 12; i++) {
            int e = e0 + i * 256 + t;
            if (e < N_EDGES) atomicAdd(&h[ei[N_EDGES + e] >> 6], 1);
        }
        __syncthreads();
        for (int b = t; b < NBINS; b += 256) {
            int c = h[b];
            gbase[b] = c ? atomicAdd(&bin_cnt[b], c) : 0;
            h[b] = 0;
        }
        __syncthreads();
#pragma unroll
        for (int i = 0; i < 12; i++) {
            int e = e0 + i * 256 + t;
            if (e < N_EDGES) {
                int s = ei[e];
                int d = ei[N_EDGES + e];
                int bin = d >> 6;
                int p = gbase[bin] + atomicAdd(&h[bin], 1);
                if (p < BINCAP)                   // hardening: never write OOB
                    eb[bin * BINCAP + p] = (s << 6) | (d & 63);
            }
        }
        return;
    }
    // ---- prep part
    int idx = (blockIdx.x - FILL_BLOCKS) * 256 + t;
    if (idx < 49152) {                                  // Wt[n][k] = bf16(Wcat[k][n])
        int k = idx % 192;
        int n = idx / 192;
        float v = (k < 96) ? Wrel[k * 256 + n] : Wroot[(k - 96) * 256 + n];
        wt[idx] = f2bf(v);
    }
    if (idx < 16384) {
        reinterpret_cast<float4*>(g)[idx] = make_float4(0.f, 0.f, 0.f, 0.f);
    }
    if (idx < 256 * 768) out[idx] = b2[idx % 768];      // bias-init for split-K mlp2
    if (idx < 400000) {                                 // column planes for k_agg
        int p    = idx / 50000;
        int node = idx - p * 50000;
        const float4* q = reinterpret_cast<const float4*>(x + node * 96 + p * 12);
        float4 f0 = q[0], f1 = q[1], f2 = q[2];
        ushort8 r0;
        ushort8 r1;
        r0[0] = f2bf(f0.x); r0[1] = f2bf(f0.y); r0[2] = f2bf(f0.z); r0[3] = f2bf(f0.w);
        r0[4] = f2bf(f1.x); r0[5] = f2bf(f1.y); r0[6] = f2bf(f1.z); r0[7] = f2bf(f1.w);
        r1[0] = f2bf(f2.x); r1[1] = f2bf(f2.y); r1[2] = f2bf(f2.z); r1[3] = f2bf(f2.w);
        r1[4] = 0; r1[5] = 0; r1[6] = 0; r1[7] = 0;     // pad cols 12..15
        unsigned short* dp = xbp + p * PLANE + node * 16;
        *reinterpret_cast<ushort8*>(dp)     = r0;
        *reinterpret_cast<ushort8*>(dp + 8) = r1;
    }
    if (idx >= N_NODES * 96 / 8) return;
    const float4* p = reinterpret_cast<const float4*>(x) + idx * 2;
    float4 u = p[0], v = p[1];
    short8 a;
    a[0] = (short)f2bf(u.x); a[1] = (short)f2bf(u.y);
    a[2] = (short)f2bf(u.z); a[3] = (short)f2bf(u.w);
    a[4] = (short)f2bf(v.x); a[5] = (short)f2bf(v.y);
    a[6] = (short)f2bf(v.z); a[7] = (short)f2bf(v.w);
    reinterpret_cast<short8*>(xb)[idx] = a;
}

// ---------------- K2: XCD-local gather, REGISTER accumulation (no LDS
// atomics — round-4's 96 DS-atomics/edge was the 404us disaster).
// Block (bin, cg) with cg = bid&7 == XCD (measured round-robin mapping):
// each XCD reads only its own 1.6 MB plane -> L2-resident (R4 confirmed:
// FETCH 17.6 MB vs 63 MB random). Counting sort per block, then thread =
// (node, q) accumulates 4 cols in registers over the node's edge list.
__global__ __launch_bounds__(256) void k_agg(const int* __restrict__ bin_cnt,
                                             const int* __restrict__ eb,
                                             const unsigned short* __restrict__ xbp,
                                             unsigned short* __restrict__ agg) {
    __shared__ int h[64], base[64], cursor[64];
    __shared__ int list[BINCAP];
    const int bid = blockIdx.x;
    const int bin = bid >> 3, cg = bid & 7;
    const int t = threadIdx.x;
    const int total = min(bin_cnt[bin], BINCAP);
    const int* ebb = eb + bin * BINCAP;

    // ---- counting sort by local node (round-2 structure, 256 thr)
    if (t < 64) h[t] = 0;
    __syncthreads();
    for (int i = t; i < total; i += 256) atomicAdd(&h[ebb[i] & 63], 1);
    __syncthreads();
    if (t < 64) {
        int v = h[t], s = v;
#pragma unroll
        for (int dd = 1; dd < 64; dd <<= 1) {
            int o = __shfl_up(s, dd);
            if (t >= dd) s += o;
        }
        base[t] = s - v;
        cursor[t] = s - v;
    }
    __syncthreads();
    for (int i = t; i < total; i += 256) {
        int m = ebb[i];
        int p = atomicAdd(&cursor[m & 63], 1);
        list[p] = m >> 6;
    }
    __syncthreads();

    // ---- gather: thread (node = t>>2, q = t&3) sums cols [4q, 4q+4)
    // of the plane (q==3 handles pad cols, skips the write).
    {
        int node = t >> 2, q = t & 3;
        const unsigned short* xp = xbp + cg * PLANE + q * 4;
        float acc[4] = {0.f, 0.f, 0.f, 0.f};
        int deg = h[node], lb = base[node];
        int e = 0;
        for (; e + 4 <= deg; e += 4) {
            int s0 = list[lb + e],     s1 = list[lb + e + 1];
            int s2 = list[lb + e + 2], s3 = list[lb + e + 3];
            ushort4v v0 = *reinterpret_cast<const ushort4v*>(xp + s0 * 16);
            ushort4v v1 = *reinterpret_cast<const ushort4v*>(xp + s1 * 16);
            ushort4v v2 = *reinterpret_cast<const ushort4v*>(xp + s2 * 16);
            ushort4v v3 = *reinterpret_cast<const ushort4v*>(xp + s3 * 16);
#pragma unroll
            for (int j = 0; j < 4; j++)
                acc[j] += (bf2f(v0[j]) + bf2f(v1[j])) + (bf2f(v2[j]) + bf2f(v3[j]));
        }
        for (; e < deg; e++) {
            int s0 = list[lb + e];
            ushort4v v0 = *reinterpret_cast<const ushort4v*>(xp + s0 * 16);
#pragma unroll
            for (int j = 0; j < 4; j++) acc[j] += bf2f(v0[j]);
        }
        if (q < 3) {
            ushort4v r;
#pragma unroll
            for (int j = 0; j < 4; j++) r[j] = f2bf(acc[j]);
            *reinterpret_cast<ushort4v*>(
                agg + (bin * 64 + node) * 96 + cg * 12 + q * 4) = r;
        }
    }
}

// ---------------- K3: GEMM 64x256x192 + bias/relu/segment-max pool.
// One 256-thr block per bin (4 waves x 64-col slice, round-0 structure);
// A-operand rows stream from agg (cols 0..95) and xb (cols 96..191).
__global__ __launch_bounds__(256, 4) void k_gemm(const unsigned short* __restrict__ agg,
                                                 const unsigned short* __restrict__ xb,
                                                 const unsigned short* __restrict__ wt,
                                                 const float* __restrict__ b_rel,
                                                 const int* __restrict__ batch,
                                                 int* __restrict__ g_i) {
    const int b = blockIdx.x, t = threadIdx.x;
    const int lane = t & 63;
    const int wave = t >> 6;
    const int quad = lane >> 4;
    const int l15  = lane & 15;
    const int row_base = b * 64;
    const int n0 = wave * 64;

    floatx4 C[4][4];
#pragma unroll
    for (int i = 0; i < 4; i++)
#pragma unroll
        for (int j = 0; j < 4; j++) C[i][j] = (floatx4)0.0f;

#pragma unroll
    for (int kc = 0; kc < 6; kc++) {
        short8 a4[4];
#pragma unroll
        for (int mf = 0; mf < 4; mf++) {
            if (kc < 3) {
                a4[mf] = *reinterpret_cast<const short8*>(
                    agg + (row_base + mf * 16 + l15) * 96 + kc * 32 + quad * 8);
            } else {
                int r = row_base + mf * 16 + l15;
                a4[mf] = (r < N_NODES)
                    ? *reinterpret_cast<const short8*>(xb + r * 96 + (kc - 3) * 32 + quad * 8)
                    : (short8)0;
            }
        }
        short8 b4[4];
#pragma unroll
        for (int nf = 0; nf < 4; nf++)
            b4[nf] = *reinterpret_cast<const short8*>(
                wt + (n0 + nf * 16 + l15) * 192 + kc * 32 + quad * 8);
#pragma unroll
        for (int mf = 0; mf < 4; mf++)
#pragma unroll
            for (int nf = 0; nf < 4; nf++)
                C[mf][nf] = __builtin_amdgcn_mfma_f32_16x16x32_bf16(
                    a4[mf], b4[nf], C[mf][nf], 0, 0, 0);
    }

    // ---- bias + relu + segment-max pool
    bool fast = (row_base + 63 < N_NODES) && (batch[row_base] == batch[row_base + 63]);
    if (fast) {
        int gid = batch[row_base];
#pragma unroll
        for (int nf = 0; nf < 4; nf++) {
            float m = C[0][nf][0];
#pragma unroll
            for (int mf = 0; mf < 4; mf++)
#pragma unroll
                for (int r = 0; r < 4; r++) m = fmaxf(m, C[mf][nf][r]);
            m = fmaxf(m, __shfl_xor(m, 16));
            m = fmaxf(m, __shfl_xor(m, 32));
            if (quad == 0) {
                int n = n0 + nf * 16 + l15;
                float v = fmaxf(m + b_rel[n], 0.0f);
                atomicMax(&g_i[gid * 256 + n], __float_as_int(v));
            }
        }
    } else {
#pragma unroll
        for (int mf = 0; mf < 4; mf++) {
            int rb = row_base + mf * 16 + quad * 4;
            if (rb >= N_NODES) continue;
            bool merged = (rb + 3 < N_NODES) && (batch[rb] == batch[rb + 3]);
            if (merged) {
                int gid = batch[rb];
#pragma unroll
                for (int nf = 0; nf < 4; nf++) {
                    float m = fmaxf(fmaxf(C[mf][nf][0], C[mf][nf][1]),
                                    fmaxf(C[mf][nf][2], C[mf][nf][3]));
                    int n = n0 + nf * 16 + l15;
                    float v = fmaxf(m + b_rel[n], 0.0f);
                    atomicMax(&g_i[gid * 256 + n], __float_as_int(v));
                }
            } else {
                for (int r = 0; r < 4; r++) {
                    int rg = rb + r;
                    if (rg >= N_NODES) break;
                    int gid = batch[rg];
#pragma unroll
                    for (int nf = 0; nf < 4; nf++) {
                        int n = n0 + nf * 16 + l15;
                        float v = fmaxf(C[mf][nf][r] + b_rel[n], 0.0f);
                        atomicMax(&g_i[gid * 256 + n], __float_as_int(v));
                    }
                }
            }
        }
    }
}

// ---------------- K4: g2 = relu(g @ W1 + b1). Round-2 version (proven):
// 512 blocks = 2048 waves; parallelism is the lever, not reuse.
__global__ __launch_bounds__(256) void k_mlp1(const float* __restrict__ g,
                                              const float* __restrict__ W1,
                                              const float* __restrict__ b1,
                                              float* __restrict__ g2) {
    __shared__ float sg[256];
    int m = blockIdx.x;
    int n = blockIdx.y * 256 + threadIdx.x;
    int t = threadIdx.x;
    sg[t] = g[m * 256 + t];
    __syncthreads();
    float a0 = 0.f, a1 = 0.f;
#pragma unroll 4
    for (int k = 0; k < 128; k++) {
        a0 += sg[k]       * W1[k * 512 + n];
        a1 += sg[k + 128] * W1[(k + 128) * 512 + n];
    }
    g2[m * 512 + n] = fmaxf(a0 + a1 + b1[n], 0.f);
}

// ---------------- K5: out += g2 @ W2 (split-K x4, out pre-init'd with b2).
// Round-2 version (proven). NO grid.sync — cooperative sync cost ~100us (R3).
__global__ __launch_bounds__(256) void k_mlp2(const float* __restrict__ g2,
                                              const float* __restrict__ W2,
                                              float* __restrict__ out) {
    __shared__ float sg[4 * 128];
    int m0 = blockIdx.x * 4;
    int n  = blockIdx.y * 256 + threadIdx.x;
    int k0 = blockIdx.z * 128;
    int t  = threadIdx.x;
#pragma unroll
    for (int j = t; j < 512; j += 256)
        sg[j] = g2[(m0 + (j >> 7)) * 512 + k0 + (j & 127)];
    __syncthreads();
    float a[4];
#pragma unroll
    for (int i = 0; i < 4; i++) a[i] = 0.f;
#pragma unroll 4
    for (int k = 0; k < 128; k++) {
        float w = W2[(k0 + k) * 768 + n];
#pragma unroll
        for (int i = 0; i < 4; i++) a[i] += sg[i * 128 + k] * w;
    }
#pragma unroll
    for (int i = 0; i < 4; i++)
        atomicAdd(&out[(m0 + i) * 768 + n], a[i]);
}

extern "C" void kernel_launch(void* const* d_in, const int* in_sizes, int n_in,
                              void* d_out, int out_size, void* d_ws, size_t ws_size,
                              hipStream_t stream) {
    const float* x      = (const float*)d_in[0];
    const int*   ei     = (const int*)d_in[1];
    const int*   batch  = (const int*)d_in[2];
    const float* W_rel  = (const float*)d_in[3];
    const float* b_rel  = (const float*)d_in[4];
    const float* W_root = (const float*)d_in[5];
    const float* W1     = (const float*)d_in[6];
    const float* b1     = (const float*)d_in[7];
    const float* W2     = (const float*)d_in[8];
    const float* b2     = (const float*)d_in[9];
    float* out = (float*)d_out;

    char* ws = (char*)d_ws;
    unsigned short* xb  = (unsigned short*)(ws);             //  9,600,000
    unsigned short* xbp = (unsigned short*)(ws + 9600000);   // 12,800,000 (8 padded planes)
    float* g       = (float*)(ws + 22400000);                //    262,144
    int* bin_cnt   = (int*)  (ws + 22662144);                //      3,136 (784 ints)
    int* eb        = (int*)  (ws + 22665280);                //  4,804,608 (782*1536*4)
    unsigned short* agg = (unsigned short*)(ws + 27469888);  //  9,609,216 (782*64*96*2)
    float* g2      = (float*)(ws + 37079104);                //    524,288
    unsigned short* wt = (unsigned short*)(ws + 37603392);   //     98,304
    // total ~37.7 MB

    hipMemsetAsync(bin_cnt, 0, 784 * sizeof(int), stream);
    k_prep_fill<<<FILL_BLOCKS + 2344, 256, 0, stream>>>(x, xb, xbp, W_rel, W_root,
                                                        wt, g, b2, out, ei, bin_cnt, eb);
    k_agg<<<NBINS * 8, 256, 0, stream>>>(bin_cnt, eb, xbp, agg);
    k_gemm<<<NBINS, 256, 0, stream>>>(agg, xb, wt, b_rel, batch, (int*)g);
    k_mlp1<<<dim3(256, 2), 256, 0, stream>>>(g, W1, b1, g2);
    k_mlp2<<<dim3(64, 3, 4), 256, 0, stream>>>(g2, W2, out);
}